// Round 10
// baseline (2031.180 us; speedup 1.0000x reference)
//
#include <hip/hip_runtime.h>
#include <hip/hip_cooperative_groups.h>
#include <cstdint>
#include <cstddef>

// GAT 2-layer (N=8192, D=256), flash softmax with rank-1 scores, bf16 MFMA PV.
// R10: entire pipeline fused into ONE cooperative kernel (512 blocks x 256 thr,
// 2 blocks/CU co-resident, grid.sync() between phases) to restore rocprof
// visibility (top-1 dispatch = the whole pipeline) and kill launch gaps.
// Phase bodies are the proven R9 kernels refactored as __device__ functions.
// Fallback: if cooperative launch fails, replay the R9 multi-kernel sequence.
// ws (64 MB): Wh @0 (8) | bits @8 (8) | bitsT @16 (8) | small @24 | Bpack @25 (4)
//             | pout @32 (4 x 8 MB k-split partials)

#define ALPHA 0.2f
#define NN 8192
#define DD 256

namespace cg = cooperative_groups;

typedef __attribute__((ext_vector_type(8))) short short8;
typedef __attribute__((ext_vector_type(4))) float f32x4;

__device__ __forceinline__ unsigned bf16rne(float x) {
    union { float f; unsigned u; } c; c.f = x;
    return (c.u + 0x7fffu + ((c.u >> 16) & 1u)) >> 16;
}

#if __has_builtin(__builtin_amdgcn_cvt_pk_bf16_f32)
__device__ __forceinline__ unsigned pk_bf16(float a, float b) {
    return __builtin_bit_cast(unsigned, __builtin_amdgcn_cvt_pk_bf16_f32(a, b));
}
#else
__device__ __forceinline__ unsigned pk_bf16(float a, float b) {
    return bf16rne(a) | (bf16rne(b) << 16);
}
#endif

// ================= phase bodies (proven R9 logic) =================

// one adjacency row -> 128 u64 mask words (call with wave-uniform row)
__device__ __forceinline__ void packbits_dev(const int* __restrict__ adj,
                                             uint64_t* __restrict__ bits,
                                             int row, int lane) {
    const int* rowp = adj + (size_t)row * NN;
    uint64_t* dst = bits + (size_t)row * 128;
    for (int it = 0; it < 32; it++) {
        const int* p = rowp + it * 256;
        int a0 = p[lane];
        int a1 = p[64 + lane];
        int a2 = p[128 + lane];
        int a3 = p[192 + lane];
        uint64_t m0 = __ballot(a0 != 0);
        uint64_t m1 = __ballot(a1 != 0);
        uint64_t m2 = __ballot(a2 != 0);
        uint64_t m3 = __ballot(a3 != 0);
        if (lane == 0) {
            dst[it * 4 + 0] = m0; dst[it * 4 + 1] = m1;
            dst[it * 4 + 2] = m2; dst[it * 4 + 3] = m3;
        }
    }
}

// bits [i][w] -> bitsT [w][i], job in [0,512): 64x64 dword tile
__device__ __forceinline__ void transp_dev(const uint32_t* __restrict__ bits32,
                                           uint32_t* __restrict__ bitsT,
                                           int job, unsigned char* smem, int t) {
    uint32_t (*tile)[65] = (uint32_t (*)[65])smem;   // 16640 B
    const int i0 = (job >> 2) * 64;
    const int w0 = (job & 3) * 64;
#pragma unroll
    for (int p = 0; p < 4; p++) {
        int r = (t >> 4) + 16 * p;
        int c4 = (t & 15) * 4;
        uint4 v = *(const uint4*)(bits32 + (size_t)(i0 + r) * 256 + w0 + c4);
        tile[r][c4 + 0] = v.x; tile[r][c4 + 1] = v.y;
        tile[r][c4 + 2] = v.z; tile[r][c4 + 3] = v.w;
    }
    __syncthreads();
#pragma unroll
    for (int p = 0; p < 4; p++) {
        int wr = (t >> 4) + 16 * p;
        int i4 = (t & 15) * 4;
        uint4 o = {tile[i4][wr], tile[i4 + 1][wr], tile[i4 + 2][wr], tile[i4 + 3][wr]};
        *(uint4*)(bitsT + (size_t)(w0 + wr) * NN + i0 + i4) = o;
    }
}

// Wh[32 x 64] tile of A@B + Bpack pack; job in [0,1024): m0=(job>>2)*32, cq=job&3
__device__ __forceinline__ void gemm_dev(const float* __restrict__ A,
                                         const float* __restrict__ B,
                                         float* __restrict__ C,
                                         unsigned short* __restrict__ Bpack,
                                         int job, unsigned char* smem, int t) {
    float (*At)[36] = (float (*)[36])smem;                 // 4608 B
    float2 (*Bs)[32] = (float2 (*)[32])(smem + 4608);      // 8192 B
    const int m0 = (job >> 2) * 32;
    const int cq = job & 3;
    const int r0 = (t >> 5) * 4;
    const int cl = t & 31;
    float acc[4][2];
#pragma unroll
    for (int i = 0; i < 4; i++) { acc[i][0] = 0.f; acc[i][1] = 0.f; }

    for (int k0 = 0; k0 < DD; k0 += 32) {
        {
            int row = t >> 3, kq = t & 7;
            float4 v = *(const float4*)(A + (size_t)(m0 + row) * DD + k0 + kq * 4);
            At[kq * 4 + 0][row] = v.x; At[kq * 4 + 1][row] = v.y;
            At[kq * 4 + 2][row] = v.z; At[kq * 4 + 3][row] = v.w;
        }
#pragma unroll
        for (int l2 = 0; l2 < 2; l2++) {
            int fi = l2 * 256 + t;
            int br = fi >> 4, bc4 = fi & 15;      // 32 k-rows x 16 float4 (64 cols)
            float4 v = *(const float4*)(B + (size_t)(k0 + br) * DD + cq * 64 + bc4 * 4);
            Bs[br][bc4 * 2] = {v.x, v.y};
            Bs[br][bc4 * 2 + 1] = {v.z, v.w};
        }
        __syncthreads();
#pragma unroll
        for (int k = 0; k < 32; k++) {
            float4 a0 = *(const float4*)&At[k][r0];
            float2 b = Bs[k][cl];
            float av[4] = {a0.x, a0.y, a0.z, a0.w};
#pragma unroll
            for (int i = 0; i < 4; i++) {
                acc[i][0] += av[i] * b.x;
                acc[i][1] += av[i] * b.y;
            }
        }
        __syncthreads();
    }
#pragma unroll
    for (int i = 0; i < 4; i++) {
        float2 v = {acc[i][0], acc[i][1]};
        *(float2*)(C + (size_t)(m0 + r0 + i) * DD + cq * 64 + cl * 2) = v;
    }
    const int jt = m0 >> 5;
    const int lq = ((r0 >> 3) & 3) * 16;
    const int i8 = r0 & 4;
#pragma unroll
    for (int cc = 0; cc < 2; cc++) {
        int c = cq * 64 + cl * 2 + cc;
        int ct = c >> 4;
        int lane = lq + (c & 15);
        uint2 pk;
        pk.x = pk_bf16(acc[0][cc], acc[1][cc]);
        pk.y = pk_bf16(acc[2][cc], acc[3][cc]);
        *(uint2*)(Bpack + ((size_t)(jt * 16 + ct) * 64 + lane) * 8 + i8) = pk;
    }
}

// one row of s/d dots + F/H exps (call with wave-uniform row)
__device__ __forceinline__ void rowdots_dev(const float* __restrict__ Wh,
                                            const float* __restrict__ a_src,
                                            const float* __restrict__ a_dst,
                                            float* __restrict__ s,
                                            float* __restrict__ dd,
                                            float* __restrict__ FH,
                                            int row, int lane) {
    float4 w = *(const float4*)(Wh + (size_t)row * DD + lane * 4);
    float4 as = *(const float4*)(a_src + lane * 4);
    float4 ad = *(const float4*)(a_dst + lane * 4);
    float ss = w.x * as.x + w.y * as.y + w.z * as.z + w.w * as.w;
    float sd = w.x * ad.x + w.y * ad.y + w.z * ad.z + w.w * ad.w;
#pragma unroll
    for (int off = 32; off; off >>= 1) {
        ss += __shfl_down(ss, off);
        sd += __shfl_down(sd, off);
    }
    if (lane == 0) {
        s[row] = ss; dd[row] = sd;
        FH[2 * row] = __expf(sd);
        FH[2 * row + 1] = __expf(ALPHA * sd);
    }
}

// 8 rows of softmax stats; job i0 = 8-row base
__device__ __forceinline__ void rowstats_dev(const uint32_t* __restrict__ bits32,
                                             const float* __restrict__ s,
                                             const float* __restrict__ dd,
                                             const float* __restrict__ FH,
                                             float* __restrict__ Ep,
                                             float* __restrict__ Gp,
                                             int i0, unsigned char* smem, int t) {
    uint32_t* smk = (uint32_t*)smem;                       // 8192 B
    float (*red)[8] = (float (*)[8])(smem + 8192);         // 128 B
    float* sEm = (float*)(smem + 8192 + 128);
    float* sEa = (float*)(smem + 8192 + 160);
    const int wave = t >> 6, lane = t & 63;
    {
        const uint4* src = (const uint4*)(bits32 + (size_t)i0 * 256);
        uint4* d = (uint4*)smk;
        d[t] = src[t];
        d[t + 256] = src[t + 256];
    }
    __syncthreads();

    float mx[8];
#pragma unroll
    for (int r = 0; r < 8; r++) mx[r] = -3.0e38f;
#pragma unroll
    for (int q = 0; q < 8; q++) {
        float4 v = *(const float4*)(dd + 4 * (t + 256 * q));
        const int wq = 32 * q + (t >> 3);
        const int sh = (t & 7) * 4;
#pragma unroll
        for (int r = 0; r < 8; r++) {
            uint32_t b = smk[r * 256 + wq] >> sh;
            mx[r] = fmaxf(mx[r], (b & 1u) ? v.x : -3.0e38f);
            mx[r] = fmaxf(mx[r], (b & 2u) ? v.y : -3.0e38f);
            mx[r] = fmaxf(mx[r], (b & 4u) ? v.z : -3.0e38f);
            mx[r] = fmaxf(mx[r], (b & 8u) ? v.w : -3.0e38f);
        }
    }
#pragma unroll
    for (int r = 0; r < 8; r++) {
#pragma unroll
        for (int off = 32; off; off >>= 1) mx[r] = fmaxf(mx[r], __shfl_down(mx[r], off));
    }
    if (lane == 0) {
#pragma unroll
        for (int r = 0; r < 8; r++) red[wave][r] = mx[r];
    }
    __syncthreads();
    if (t < 8) {
        float dmax = fmaxf(fmaxf(red[0][t], red[1][t]), fmaxf(red[2][t], red[3][t]));
        float si = s[i0 + t];
        float e = si + dmax;
        float m = e >= 0.f ? e : ALPHA * e;
        sEm[t] = __expf(si - m);
        sEa[t] = __expf(ALPHA * si - m);
    }
    __syncthreads();
    float em[8], ea[8], sm[8];
#pragma unroll
    for (int r = 0; r < 8; r++) { em[r] = sEm[r]; ea[r] = sEa[r]; sm[r] = 0.f; }

#pragma unroll
    for (int q = 0; q < 16; q++) {
        float4 v = *(const float4*)(FH + 4 * (t + 256 * q));
        const int wq = 16 * q + (t >> 4);
        const int sh = (t & 15) * 2;
#pragma unroll
        for (int r = 0; r < 8; r++) {
            uint32_t b = smk[r * 256 + wq] >> sh;
            float c0 = fmaxf(em[r] * v.x, ea[r] * v.y);
            float c1 = fmaxf(em[r] * v.z, ea[r] * v.w);
            sm[r] += (b & 1u) ? c0 : 0.f;
            sm[r] += (b & 2u) ? c1 : 0.f;
        }
    }
#pragma unroll
    for (int r = 0; r < 8; r++) {
#pragma unroll
        for (int off = 32; off; off >>= 1) sm[r] += __shfl_down(sm[r], off);
    }
    __syncthreads();
    if (lane == 0) {
#pragma unroll
        for (int r = 0; r < 8; r++) red[wave][r] = sm[r];
    }
    __syncthreads();
    if (t < 8) {
        float rl = 1.0f / (red[0][t] + red[1][t] + red[2][t] + red[3][t]);
        Ep[i0 + t] = rl * sEm[t];
        Gp[i0 + t] = rl * sEa[t];
    }
}

// pv job in [0,512): ks=job&3, ch=(job>>2)&1, i0=(job>>3)*128 (R9 v5 body)
__device__ __forceinline__ void pv_dev(const unsigned short* __restrict__ Bpack,
                                       const uint32_t* __restrict__ bitsT,
                                       const float* __restrict__ FH,
                                       const float* __restrict__ Ep,
                                       const float* __restrict__ Gp,
                                       float* __restrict__ pout,
                                       int job, unsigned char* smem, int t) {
    unsigned short (*fragA)[4096] = (unsigned short (*)[4096])smem;   // 32768 B
    const int w = t >> 6, l = t & 63;
    const int ks = job & 3;
    const int ch = (job >> 2) & 1;
    const int i0 = (job >> 3) * 128;
    const int kbase = ks * 64;
    const int ct0 = ch * 8;
    const int rg = w >> 1, cg = w & 1;

    const int rlane = t & 31;
    const int kq = t >> 5;
    float Epv[4], Gpv[4];
#pragma unroll
    for (int e = 0; e < 4; e++) {
        Epv[e] = Ep[i0 + rlane + 32 * e];
        Gpv[e] = Gp[i0 + rlane + 32 * e];
    }
    const int lanebase = (kq >> 1) * 16 + (rlane & 15);
    const int rbbase = rlane >> 4;
    const int khi = kq & 1;

    auto gen = [&](int cc, int ci) {
        const int jj = cc * 32 + kq * 4;
        float4 fh0 = *(const float4*)(FH + 2 * (size_t)jj);
        float4 fh1 = *(const float4*)(FH + 2 * (size_t)jj + 4);
        const uint32_t* bt = bitsT + (size_t)cc * NN + i0 + rlane;
        uint2* dst = (uint2*)&fragA[ci][0];
#pragma unroll
        for (int e = 0; e < 4; e++) {
            uint32_t b = bt[32 * e] >> (kq * 4);
            float p0 = (b & 1u) ? fmaxf(Epv[e] * fh0.x, Gpv[e] * fh0.y) : 0.f;
            float p1 = (b & 2u) ? fmaxf(Epv[e] * fh0.z, Gpv[e] * fh0.w) : 0.f;
            float p2 = (b & 4u) ? fmaxf(Epv[e] * fh1.x, Gpv[e] * fh1.y) : 0.f;
            float p3 = (b & 8u) ? fmaxf(Epv[e] * fh1.z, Gpv[e] * fh1.w) : 0.f;
            uint2 pk;
            pk.x = pk_bf16(p0, p1);
            pk.y = pk_bf16(p2, p3);
            dst[((rbbase + 2 * e) * 64 + lanebase) * 2 + khi] = pk;
        }
    };

    const unsigned short* bbase = Bpack + ((size_t)(ct0 + cg * 4) * 64 + l) * 8;

    f32x4 acc[4][4];
#pragma unroll
    for (int i = 0; i < 4; i++)
#pragma unroll
        for (int q = 0; q < 4; q++) acc[i][q] = (f32x4){0.f, 0.f, 0.f, 0.f};

    short8 Bc[4];
    {
        const unsigned short* bp = bbase + (size_t)kbase * 8192;
#pragma unroll
        for (int q = 0; q < 4; q++) Bc[q] = *(const short8*)(bp + q * 512);
    }

    for (int b = 0; b < 16; b++) {
#pragma unroll
        for (int ci = 0; ci < 4; ci++) gen(kbase + 4 * b + ci, ci);
        __syncthreads();
#pragma unroll
        for (int ci = 0; ci < 4; ci++) {
            const int cn = kbase + ((4 * b + ci + 1) & 63);
            const unsigned short* bp = bbase + (size_t)cn * 8192;
            short8 Bn[4];
#pragma unroll
            for (int q = 0; q < 4; q++) Bn[q] = *(const short8*)(bp + q * 512);
            short8 a[4];
#pragma unroll
            for (int ri = 0; ri < 4; ri++)
                a[ri] = *(const short8*)&fragA[ci][((rg * 4 + ri) * 64 + l) * 8];
#pragma unroll
            for (int ri = 0; ri < 4; ri++)
#pragma unroll
                for (int qi = 0; qi < 4; qi++)
                    acc[ri][qi] = __builtin_amdgcn_mfma_f32_16x16x32_bf16(a[ri], Bc[qi],
                                                                          acc[ri][qi], 0, 0, 0);
#pragma unroll
            for (int q = 0; q < 4; q++) Bc[q] = Bn[q];
        }
        __syncthreads();
    }

    float* outp = pout + (size_t)ks * NN * DD;
#pragma unroll
    for (int ri = 0; ri < 4; ri++) {
        const int orow = i0 + rg * 64 + ri * 16 + (l >> 4) * 4;
#pragma unroll
        for (int qi = 0; qi < 4; qi++) {
            const int ocol = (ct0 + cg * 4 + qi) * 16 + (l & 15);
#pragma unroll
            for (int r = 0; r < 4; r++)
                outp[(size_t)(orow + r) * DD + ocol] = acc[ri][qi][r];
        }
    }
}

// one float4-granule of out = relu(p0+p1+p2+p3); gid in [0, NN*DD/4)
__device__ __forceinline__ void combine_dev(const float* __restrict__ p,
                                            float* __restrict__ out, size_t gid) {
    const size_t S = (size_t)NN * DD / 4;
    float4 a = ((const float4*)p)[gid];
    float4 b = ((const float4*)p)[gid + S];
    float4 c = ((const float4*)p)[gid + 2 * S];
    float4 d = ((const float4*)p)[gid + 3 * S];
    float4 o;
    o.x = fmaxf(a.x + b.x + c.x + d.x, 0.f);
    o.y = fmaxf(a.y + b.y + c.y + d.y, 0.f);
    o.z = fmaxf(a.z + b.z + c.z + d.z, 0.f);
    o.w = fmaxf(a.w + b.w + c.w + d.w, 0.f);
    ((float4*)out)[gid] = o;
}

// ================= fused cooperative kernel =================
__global__ __launch_bounds__(256, 2) void fused(const float* x, const int* adj,
                                                const float* W1, const float* a1s, const float* a1d,
                                                const float* W2, const float* a2s, const float* a2d,
                                                float* out,
                                                uint64_t* bits, uint32_t* bitsT,
                                                float* s, float* dd, float* Ep, float* Gp, float* FH,
                                                unsigned short* Bpack, float* Wh, float* pout) {
    __shared__ __align__(16) unsigned char smem[32768];
    cg::grid_group gg = cg::this_grid();
    const int bx = blockIdx.x;
    const int t = threadIdx.x;
    const int wave = t >> 6, lane = t & 63;
    const uint32_t* bits32 = (const uint32_t*)bits;

    // phase 0: packbits (16 rows/block)
#pragma unroll
    for (int rr = 0; rr < 4; rr++)
        packbits_dev(adj, bits, bx * 16 + wave * 4 + rr, lane);
    __threadfence();
    gg.sync();

    // phase 1 head: bits transpose (independent of gemm below; no sync between)
    transp_dev(bits32, bitsT, bx, smem, t);
    __syncthreads();   // protect smem reuse by gemm

    for (int ell = 0; ell < 2; ell++) {
        const float* A_in = ell ? (const float*)out : x;
        const float* W = ell ? W2 : W1;
        const float* asrc = ell ? a2s : a1s;
        const float* adst = ell ? a2d : a1d;

        // gemm: 2 jobs/block
        gemm_dev(A_in, W, Wh, Bpack, bx * 2 + 0, smem, t);
        gemm_dev(A_in, W, Wh, Bpack, bx * 2 + 1, smem, t);
        __threadfence();
        gg.sync();

        // rowdots: 16 rows/block
#pragma unroll
        for (int jj = 0; jj < 4; jj++)
            rowdots_dev(Wh, asrc, adst, s, dd, FH, bx * 16 + jj * 4 + wave, lane);
        __threadfence();
        gg.sync();

        // rowstats: 2 jobs/block
        rowstats_dev(bits32, s, dd, FH, Ep, Gp, (bx * 2 + 0) * 8, smem, t);
        rowstats_dev(bits32, s, dd, FH, Ep, Gp, (bx * 2 + 1) * 8, smem, t);
        __threadfence();
        gg.sync();

        // pv: 1 job/block
        pv_dev(Bpack, bitsT, FH, Ep, Gp, pout, bx, smem, t);
        __threadfence();
        gg.sync();

        // combine: 4 jobs/block
#pragma unroll
        for (int jj = 0; jj < 4; jj++)
            combine_dev(pout, out, (size_t)(bx * 4 + jj) * 256 + t);
        __threadfence();
        gg.sync();
    }
}

// ================= standalone fallback kernels (R9 sequence) =================
__global__ __launch_bounds__(256) void k_packbits(const int* adj, uint64_t* bits) {
    packbits_dev(adj, bits, blockIdx.x * 4 + (threadIdx.x >> 6), threadIdx.x & 63);
}
__global__ __launch_bounds__(256) void k_transp(const uint32_t* bits32, uint32_t* bitsT) {
    __shared__ __align__(16) unsigned char smem[16640];
    transp_dev(bits32, bitsT, blockIdx.x, smem, threadIdx.x);
}
__global__ __launch_bounds__(256) void k_gemm(const float* A, const float* B, float* C,
                                              unsigned short* Bpack) {
    __shared__ __align__(16) unsigned char smem[12800];
    gemm_dev(A, B, C, Bpack, blockIdx.x, smem, threadIdx.x);
}
__global__ __launch_bounds__(256) void k_rowdots(const float* Wh, const float* as,
                                                 const float* ad, float* s, float* dd, float* FH) {
    rowdots_dev(Wh, as, ad, s, dd, FH, blockIdx.x * 4 + (threadIdx.x >> 6), threadIdx.x & 63);
}
__global__ __launch_bounds__(256) void k_rowstats(const uint32_t* bits32, const float* s,
                                                  const float* dd, const float* FH,
                                                  float* Ep, float* Gp) {
    __shared__ __align__(16) unsigned char smem[8384];
    rowstats_dev(bits32, s, dd, FH, Ep, Gp, blockIdx.x * 8, smem, threadIdx.x);
}
__global__ __launch_bounds__(256, 3) void k_pv(const unsigned short* Bpack, const uint32_t* bitsT,
                                               const float* FH, const float* Ep, const float* Gp,
                                               float* pout) {
    __shared__ __align__(16) unsigned char smem[32768];
    pv_dev(Bpack, bitsT, FH, Ep, Gp, pout, blockIdx.x, smem, threadIdx.x);
}
__global__ __launch_bounds__(256) void k_combine(const float* p, float* out) {
    combine_dev(p, out, (size_t)blockIdx.x * 256 + threadIdx.x);
}

extern "C" void kernel_launch(void* const* d_in, const int* in_sizes, int n_in,
                              void* d_out, int out_size, void* d_ws, size_t ws_size,
                              hipStream_t stream) {
    const float* x   = (const float*)d_in[0];
    const int* adj   = (const int*)d_in[1];
    const float* W1  = (const float*)d_in[2];
    const float* a1s = (const float*)d_in[3];
    const float* a1d = (const float*)d_in[4];
    const float* W2  = (const float*)d_in[5];
    const float* a2s = (const float*)d_in[6];
    const float* a2d = (const float*)d_in[7];
    float* out = (float*)d_out;

    char* ws = (char*)d_ws;
    const size_t MB = 1024ull * 1024ull;
    float*          Wh    = (float*)(ws);                    // 8 MB
    uint64_t*       bits  = (uint64_t*)(ws + 8 * MB);        // 8 MB
    uint32_t*       bits32= (uint32_t*)bits;
    uint32_t*       bitsT = (uint32_t*)(ws + 16 * MB);       // 8 MB
    float*          sArr  = (float*)(ws + 24 * MB);
    float*          ddA   = sArr + NN;
    float*          EpA   = sArr + 2 * NN;
    float*          GpA   = sArr + 3 * NN;
    float*          FHA   = sArr + 4 * NN;                   // 2*NN floats
    unsigned short* Bpack = (unsigned short*)(ws + 25 * MB); // 4 MB
    float*          pout  = (float*)(ws + 32 * MB);          // 32 MB (4 partials)

    void* args[] = {(void*)&x, (void*)&adj, (void*)&W1, (void*)&a1s, (void*)&a1d,
                    (void*)&W2, (void*)&a2s, (void*)&a2d, (void*)&out,
                    (void*)&bits, (void*)&bitsT, (void*)&sArr, (void*)&ddA,
                    (void*)&EpA, (void*)&GpA, (void*)&FHA, (void*)&Bpack,
                    (void*)&Wh, (void*)&pout};
    hipError_t err = hipLaunchCooperativeKernel((const void*)fused, dim3(512), dim3(256),
                                                args, 0, stream);
    if (err != hipSuccess) {
        // fallback: R9 multi-kernel sequence
        k_packbits<<<dim3(2048), dim3(256), 0, stream>>>(adj, bits);
        k_transp<<<dim3(512), dim3(256), 0, stream>>>(bits32, bitsT);
        for (int ell = 0; ell < 2; ell++) {
            const float* A_in = ell ? (const float*)out : x;
            const float* W = ell ? W2 : W1;
            const float* asrc = ell ? a2s : a1s;
            const float* adst = ell ? a2d : a1d;
            k_gemm<<<dim3(1024), dim3(256), 0, stream>>>(A_in, W, Wh, Bpack);
            k_rowdots<<<dim3(2048), dim3(256), 0, stream>>>(Wh, asrc, adst, sArr, ddA, FHA);
            k_rowstats<<<dim3(1024), dim3(256), 0, stream>>>(bits32, sArr, ddA, FHA, EpA, GpA);
            k_pv<<<dim3(512), dim3(256), 0, stream>>>(Bpack, bitsT, FHA, EpA, GpA, pout);
            k_combine<<<dim3(2048), dim3(256), 0, stream>>>(pout, out);
        }
    }
}

// Round 11
// 670.086 us; speedup vs baseline: 3.0312x; 3.0312x over previous
//
#include <hip/hip_runtime.h>
#include <cstdint>
#include <cstddef>

// GAT 2-layer (N=8192, D=256), flash softmax with rank-1 scores, bf16 MFMA PV.
// Identities:
//   m_i = leaky(s_i + max_{adj} d_j)        (leaky monotone)
//   exp(leaky(x)) = max(e^x, e^{a x})
//   p_ij = adj ? max(Ep_i*F_j, Gp_i*H_j) : 0,  F=e^d, H=e^{a d} (FH interleaved),
//   Ep = rl*e^{s-m}, Gp = rl*e^{a s-m}.
// R11 pv v7: BARRIER-FREE. Wave = 32 rows x 64 cols x K/4; both A-frags generated
// in the consuming wave's registers (bitsT dword + broadcast FH loads), B-frags +
// bits prefetched one chunk ahead, 8 MFMAs/chunk, no LDS, no __syncthreads.
// 1024 blocks, 4 blocks/CU (16 waves/CU) -- latency hidden by TLP, not sync.
// rowstats: 4 rows/block x 2048 blocks (8 blocks/CU, 32 waves/CU).
// ws (64 MB): Wh @0 (8) | bits @8 (8) | bitsT @16 (8) | small @24 | Bpack @25 (4)
//             | pout @32 (4 x 8 MB k-split partials)

#define ALPHA 0.2f
#define NN 8192
#define DD 256

typedef __attribute__((ext_vector_type(8))) short short8;
typedef __attribute__((ext_vector_type(4))) float f32x4;

__device__ __forceinline__ unsigned bf16rne(float x) {
    union { float f; unsigned u; } c; c.f = x;
    return (c.u + 0x7fffu + ((c.u >> 16) & 1u)) >> 16;
}

#if __has_builtin(__builtin_amdgcn_cvt_pk_bf16_f32)
__device__ __forceinline__ unsigned pk_bf16(float a, float b) {
    return __builtin_bit_cast(unsigned, __builtin_amdgcn_cvt_pk_bf16_f32(a, b));
}
#else
__device__ __forceinline__ unsigned pk_bf16(float a, float b) {
    return bf16rne(a) | (bf16rne(b) << 16);
}
#endif

// ---------------- packbits: adj int32 [8192][8192] -> bits [8192][128] u64 ----------------
__global__ __launch_bounds__(256) void packbits(const int* __restrict__ adj,
                                                uint64_t* __restrict__ bits) {
    const int wid = blockIdx.x * 4 + (threadIdx.x >> 6);
    const int lane = threadIdx.x & 63;
    const int* rowp = adj + (size_t)wid * NN;
    uint64_t* dst = bits + (size_t)wid * 128;
    for (int it = 0; it < 32; it++) {
        const int* p = rowp + it * 256;
        int a0 = p[lane];
        int a1 = p[64 + lane];
        int a2 = p[128 + lane];
        int a3 = p[192 + lane];
        uint64_t m0 = __ballot(a0 != 0);
        uint64_t m1 = __ballot(a1 != 0);
        uint64_t m2 = __ballot(a2 != 0);
        uint64_t m3 = __ballot(a3 != 0);
        if (lane == 0) {
            dst[it * 4 + 0] = m0; dst[it * 4 + 1] = m1;
            dst[it * 4 + 2] = m2; dst[it * 4 + 3] = m3;
        }
    }
}

// ---------------- bits [i][w] -> bitsT [w][i] (64x64 dword tiles) ----------------
__global__ __launch_bounds__(256) void transp_bits(const uint32_t* __restrict__ bits32,
                                                   uint32_t* __restrict__ bitsT) {
    __shared__ uint32_t tile[64][65];
    const int t = threadIdx.x;
    const int i0 = (int)(blockIdx.x >> 2) * 64;
    const int w0 = (int)(blockIdx.x & 3) * 64;
#pragma unroll
    for (int p = 0; p < 4; p++) {
        int r = (t >> 4) + 16 * p;
        int c4 = (t & 15) * 4;
        uint4 v = *(const uint4*)(bits32 + (size_t)(i0 + r) * 256 + w0 + c4);
        tile[r][c4 + 0] = v.x; tile[r][c4 + 1] = v.y;
        tile[r][c4 + 2] = v.z; tile[r][c4 + 3] = v.w;
    }
    __syncthreads();
#pragma unroll
    for (int p = 0; p < 4; p++) {
        int wr = (t >> 4) + 16 * p;
        int i4 = (t & 15) * 4;
        uint4 o = {tile[i4][wr], tile[i4 + 1][wr], tile[i4 + 2][wr], tile[i4 + 3][wr]};
        *(uint4*)(bitsT + (size_t)(w0 + wr) * NN + i0 + i4) = o;
    }
}

// ---------------- GEMM: Wh[8192 x 256] = A @ B[256 x 256], fp32; packs Bpack ----------------
// 1024 blocks (4/CU): 256 row-tiles (32) x 4 col-quarters (64 cols).
__global__ __launch_bounds__(256) void gemm_k256(const float* __restrict__ A,
                                                 const float* __restrict__ B,
                                                 float* __restrict__ C,
                                                 unsigned short* __restrict__ Bpack) {
    __shared__ __align__(16) float At[32][36];
    __shared__ __align__(16) float2 Bs[32][32];
    const int t = threadIdx.x;
    const int m0 = (int)(blockIdx.x >> 2) * 32;
    const int cq = blockIdx.x & 3;
    const int r0 = (t >> 5) * 4;
    const int cl = t & 31;
    float acc[4][2];
#pragma unroll
    for (int i = 0; i < 4; i++) { acc[i][0] = 0.f; acc[i][1] = 0.f; }

    for (int k0 = 0; k0 < DD; k0 += 32) {
        {
            int row = t >> 3, kq = t & 7;
            float4 v = *(const float4*)(A + (size_t)(m0 + row) * DD + k0 + kq * 4);
            At[kq * 4 + 0][row] = v.x; At[kq * 4 + 1][row] = v.y;
            At[kq * 4 + 2][row] = v.z; At[kq * 4 + 3][row] = v.w;
        }
#pragma unroll
        for (int l2 = 0; l2 < 2; l2++) {
            int fi = l2 * 256 + t;
            int br = fi >> 4, bc4 = fi & 15;      // 32 k-rows x 16 float4 (64 cols)
            float4 v = *(const float4*)(B + (size_t)(k0 + br) * DD + cq * 64 + bc4 * 4);
            Bs[br][bc4 * 2] = {v.x, v.y};
            Bs[br][bc4 * 2 + 1] = {v.z, v.w};
        }
        __syncthreads();
#pragma unroll
        for (int k = 0; k < 32; k++) {
            float4 a0 = *(const float4*)&At[k][r0];
            float2 b = Bs[k][cl];
            float av[4] = {a0.x, a0.y, a0.z, a0.w};
#pragma unroll
            for (int i = 0; i < 4; i++) {
                acc[i][0] += av[i] * b.x;
                acc[i][1] += av[i] * b.y;
            }
        }
        __syncthreads();
    }
#pragma unroll
    for (int i = 0; i < 4; i++) {
        float2 v = {acc[i][0], acc[i][1]};
        *(float2*)(C + (size_t)(m0 + r0 + i) * DD + cq * 64 + cl * 2) = v;
    }
    const int jt = m0 >> 5;
    const int lq = ((r0 >> 3) & 3) * 16;
    const int i8 = r0 & 4;
#pragma unroll
    for (int cc = 0; cc < 2; cc++) {
        int c = cq * 64 + cl * 2 + cc;
        int ct = c >> 4;
        int lane = lq + (c & 15);
        uint2 pk;
        pk.x = pk_bf16(acc[0][cc], acc[1][cc]);
        pk.y = pk_bf16(acc[2][cc], acc[3][cc]);
        *(uint2*)(Bpack + ((size_t)(jt * 16 + ct) * 64 + lane) * 8 + i8) = pk;
    }
}

// ------- s,d row dots; FH[2i]=exp(d), FH[2i+1]=exp(a*d) (1 wave/row) -------
__global__ __launch_bounds__(256) void rowdots(const float* __restrict__ Wh,
                                               const float* __restrict__ a_src,
                                               const float* __restrict__ a_dst,
                                               float* __restrict__ s,
                                               float* __restrict__ dd,
                                               float* __restrict__ FH) {
    int wave = threadIdx.x >> 6;
    int lane = threadIdx.x & 63;
    int row = blockIdx.x * 4 + wave;
    float4 w = *(const float4*)(Wh + (size_t)row * DD + lane * 4);
    float4 as = *(const float4*)(a_src + lane * 4);
    float4 ad = *(const float4*)(a_dst + lane * 4);
    float ss = w.x * as.x + w.y * as.y + w.z * as.z + w.w * as.w;
    float sd = w.x * ad.x + w.y * ad.y + w.z * ad.z + w.w * ad.w;
#pragma unroll
    for (int off = 32; off; off >>= 1) {
        ss += __shfl_down(ss, off);
        sd += __shfl_down(sd, off);
    }
    if (lane == 0) {
        s[row] = ss; dd[row] = sd;
        FH[2 * row] = __expf(sd);
        FH[2 * row + 1] = __expf(ALPHA * sd);
    }
}

// ------ rowstats v4: 4 rows/block, 2048 blocks (8/CU, 32 waves/CU) ------
__global__ __launch_bounds__(256) void rowstats(const uint32_t* __restrict__ bits32,
                                                const float* __restrict__ s,
                                                const float* __restrict__ dd,
                                                const float* __restrict__ FH,
                                                float* __restrict__ Ep,
                                                float* __restrict__ Gp) {
    __shared__ uint32_t smk[1024];          // 4 rows x 256 words
    __shared__ float red[4][4];
    __shared__ float sEm[4], sEa[4];
    const int i0 = blockIdx.x * 4;
    const int t = threadIdx.x;
    const int wave = t >> 6, lane = t & 63;
    {
        const uint4* src = (const uint4*)(bits32 + (size_t)i0 * 256);
        ((uint4*)smk)[t] = src[t];
    }
    __syncthreads();

    float mx[4];
#pragma unroll
    for (int r = 0; r < 4; r++) mx[r] = -3.0e38f;
#pragma unroll
    for (int q = 0; q < 8; q++) {
        float4 v = *(const float4*)(dd + 4 * (t + 256 * q));
        const int wq = 32 * q + (t >> 3);
        const int sh = (t & 7) * 4;
#pragma unroll
        for (int r = 0; r < 4; r++) {
            uint32_t b = smk[r * 256 + wq] >> sh;
            mx[r] = fmaxf(mx[r], (b & 1u) ? v.x : -3.0e38f);
            mx[r] = fmaxf(mx[r], (b & 2u) ? v.y : -3.0e38f);
            mx[r] = fmaxf(mx[r], (b & 4u) ? v.z : -3.0e38f);
            mx[r] = fmaxf(mx[r], (b & 8u) ? v.w : -3.0e38f);
        }
    }
#pragma unroll
    for (int r = 0; r < 4; r++) {
#pragma unroll
        for (int off = 32; off; off >>= 1) mx[r] = fmaxf(mx[r], __shfl_down(mx[r], off));
    }
    if (lane == 0) {
#pragma unroll
        for (int r = 0; r < 4; r++) red[wave][r] = mx[r];
    }
    __syncthreads();
    if (t < 4) {
        float dmax = fmaxf(fmaxf(red[0][t], red[1][t]), fmaxf(red[2][t], red[3][t]));
        float si = s[i0 + t];
        float e = si + dmax;
        float m = e >= 0.f ? e : ALPHA * e;
        sEm[t] = __expf(si - m);
        sEa[t] = __expf(ALPHA * si - m);
    }
    __syncthreads();
    float em[4], ea[4], sm[4];
#pragma unroll
    for (int r = 0; r < 4; r++) { em[r] = sEm[r]; ea[r] = sEa[r]; sm[r] = 0.f; }

#pragma unroll
    for (int q = 0; q < 16; q++) {
        float4 v = *(const float4*)(FH + 4 * (t + 256 * q));
        const int wq = 16 * q + (t >> 4);
        const int sh = (t & 15) * 2;
#pragma unroll
        for (int r = 0; r < 4; r++) {
            uint32_t b = smk[r * 256 + wq] >> sh;
            float c0 = fmaxf(em[r] * v.x, ea[r] * v.y);
            float c1 = fmaxf(em[r] * v.z, ea[r] * v.w);
            sm[r] += (b & 1u) ? c0 : 0.f;
            sm[r] += (b & 2u) ? c1 : 0.f;
        }
    }
#pragma unroll
    for (int r = 0; r < 4; r++) {
#pragma unroll
        for (int off = 32; off; off >>= 1) sm[r] += __shfl_down(sm[r], off);
    }
    __syncthreads();
    if (lane == 0) {
#pragma unroll
        for (int r = 0; r < 4; r++) red[wave][r] = sm[r];
    }
    __syncthreads();
    if (t < 4) {
        float rl = 1.0f / (red[0][t] + red[1][t] + red[2][t] + red[3][t]);
        Ep[i0 + t] = rl * sEm[t];
        Gp[i0 + t] = rl * sEa[t];
    }
}

// ---------------- pv v7: barrier-free in-register MFMA, pout[ks] = P @ Wh ----------------
// 1024 blocks x 256 thr: bx -> ks = bx&3, cg = (bx>>2)&3, ib = bx>>4.
// Wave w: rows ib*128 + w*32 (2 A-frags), cols cg*64 (4 B-frags), K = ks*2048.
// Per chunk: prefetch next B-frags + bits; FH broadcast loads at use; gen 2 A-frags
// in registers; 8 MFMAs. NO LDS, NO barriers.
__global__ __launch_bounds__(256, 4) void pv_mfma(const unsigned short* __restrict__ Bpack,
                                                  const uint32_t* __restrict__ bitsT,
                                                  const float* __restrict__ FH,
                                                  const float* __restrict__ Ep,
                                                  const float* __restrict__ Gp,
                                                  float* __restrict__ pout) {
    const int t = threadIdx.x;
    const int w = t >> 6, l = t & 63;
    const int bx = blockIdx.x;
    const int ks = bx & 3;
    const int cg = (bx >> 2) & 3;
    const int i0 = (bx >> 4) * 128 + w * 32;     // wave's 32-row base
    const int kbase = ks * 64;                   // 64 chunks per quarter

    const int rl16 = l & 15;
    const int ko = (l >> 4) * 8;                 // k-octet within 32-wide chunk
    const int r0 = i0 + rl16;
    const float Ep0 = Ep[r0], Gp0 = Gp[r0];
    const float Ep1 = Ep[r0 + 16], Gp1 = Gp[r0 + 16];

    const unsigned short* bb = Bpack + ((size_t)(cg * 4) * 64 + l) * 8;
    const uint32_t* btb = bitsT + i0 + rl16;     // + cc*NN (+16 for 2nd frag)

    f32x4 acc[2][4];
#pragma unroll
    for (int i = 0; i < 2; i++)
#pragma unroll
        for (int q = 0; q < 4; q++) acc[i][q] = (f32x4){0.f, 0.f, 0.f, 0.f};

    // ---- prefetch chunk kbase ----
    short8 Bc0, Bc1, Bc2, Bc3;
    uint32_t bw0, bw1;
    {
        const unsigned short* bp = bb + (size_t)kbase * 8192;
        Bc0 = *(const short8*)(bp);
        Bc1 = *(const short8*)(bp + 512);
        Bc2 = *(const short8*)(bp + 1024);
        Bc3 = *(const short8*)(bp + 1536);
        bw0 = btb[(size_t)kbase * NN];
        bw1 = btb[(size_t)kbase * NN + 16];
    }

    for (int jl = 0; jl < 64; jl++) {
        const int cc = kbase + jl;
        const int cn = kbase + ((jl + 1) & 63);
        // prefetch next chunk's B + bits (in flight across this chunk's compute)
        const unsigned short* bp = bb + (size_t)cn * 8192;
        short8 Bn0 = *(const short8*)(bp);
        short8 Bn1 = *(const short8*)(bp + 512);
        short8 Bn2 = *(const short8*)(bp + 1024);
        short8 Bn3 = *(const short8*)(bp + 1536);
        uint32_t bn0 = btb[(size_t)cn * NN];
        uint32_t bn1 = btb[(size_t)cn * NN + 16];

        // FH for this chunk (broadcast across 16 lanes; L1-resident, 16 KB/quarter)
        const float* fp = FH + 2 * (size_t)(cc * 32 + ko);
        float4 f0 = *(const float4*)(fp);
        float4 f1 = *(const float4*)(fp + 4);
        float4 f2 = *(const float4*)(fp + 8);
        float4 f3 = *(const float4*)(fp + 12);

        uint32_t wl0 = bw0 >> ko;
        uint32_t wl1 = bw1 >> ko;
        float p0 = (wl0 & 1u)   ? fmaxf(Ep0 * f0.x, Gp0 * f0.y) : 0.f;
        float p1 = (wl0 & 2u)   ? fmaxf(Ep0 * f0.z, Gp0 * f0.w) : 0.f;
        float p2 = (wl0 & 4u)   ? fmaxf(Ep0 * f1.x, Gp0 * f1.y) : 0.f;
        float p3 = (wl0 & 8u)   ? fmaxf(Ep0 * f1.z, Gp0 * f1.w) : 0.f;
        float p4 = (wl0 & 16u)  ? fmaxf(Ep0 * f2.x, Gp0 * f2.y) : 0.f;
        float p5 = (wl0 & 32u)  ? fmaxf(Ep0 * f2.z, Gp0 * f2.w) : 0.f;
        float p6 = (wl0 & 64u)  ? fmaxf(Ep0 * f3.x, Gp0 * f3.y) : 0.f;
        float p7 = (wl0 & 128u) ? fmaxf(Ep0 * f3.z, Gp0 * f3.w) : 0.f;
        uint4 au0 = {pk_bf16(p0, p1), pk_bf16(p2, p3), pk_bf16(p4, p5), pk_bf16(p6, p7)};
        short8 a0 = __builtin_bit_cast(short8, au0);

        float q0 = (wl1 & 1u)   ? fmaxf(Ep1 * f0.x, Gp1 * f0.y) : 0.f;
        float q1 = (wl1 & 2u)   ? fmaxf(Ep1 * f0.z, Gp1 * f0.w) : 0.f;
        float q2 = (wl1 & 4u)   ? fmaxf(Ep1 * f1.x, Gp1 * f1.y) : 0.f;
        float q3 = (wl1 & 8u)   ? fmaxf(Ep1 * f1.z, Gp1 * f1.w) : 0.f;
        float q4 = (wl1 & 16u)  ? fmaxf(Ep1 * f2.x, Gp1 * f2.y) : 0.f;
        float q5 = (wl1 & 32u)  ? fmaxf(Ep1 * f2.z, Gp1 * f2.w) : 0.f;
        float q6 = (wl1 & 64u)  ? fmaxf(Ep1 * f3.x, Gp1 * f3.y) : 0.f;
        float q7 = (wl1 & 128u) ? fmaxf(Ep1 * f3.z, Gp1 * f3.w) : 0.f;
        uint4 au1 = {pk_bf16(q0, q1), pk_bf16(q2, q3), pk_bf16(q4, q5), pk_bf16(q6, q7)};
        short8 a1 = __builtin_bit_cast(short8, au1);

        acc[0][0] = __builtin_amdgcn_mfma_f32_16x16x32_bf16(a0, Bc0, acc[0][0], 0, 0, 0);
        acc[1][0] = __builtin_amdgcn_mfma_f32_16x16x32_bf16(a1, Bc0, acc[1][0], 0, 0, 0);
        acc[0][1] = __builtin_amdgcn_mfma_f32_16x16x32_bf16(a0, Bc1, acc[0][1], 0, 0, 0);
        acc[1][1] = __builtin_amdgcn_mfma_f32_16x16x32_bf16(a1, Bc1, acc[1][1], 0, 0, 0);
        acc[0][2] = __builtin_amdgcn_mfma_f32_16x16x32_bf16(a0, Bc2, acc[0][2], 0, 0, 0);
        acc[1][2] = __builtin_amdgcn_mfma_f32_16x16x32_bf16(a1, Bc2, acc[1][2], 0, 0, 0);
        acc[0][3] = __builtin_amdgcn_mfma_f32_16x16x32_bf16(a0, Bc3, acc[0][3], 0, 0, 0);
        acc[1][3] = __builtin_amdgcn_mfma_f32_16x16x32_bf16(a1, Bc3, acc[1][3], 0, 0, 0);

        Bc0 = Bn0; Bc1 = Bn1; Bc2 = Bn2; Bc3 = Bn3;
        bw0 = bn0; bw1 = bn1;
    }

    float* outp = pout + (size_t)ks * NN * DD;
    // C layout: col = l&15, row = (l>>4)*4 + r
#pragma unroll
    for (int rb = 0; rb < 2; rb++) {
        const int orow = i0 + rb * 16 + (l >> 4) * 4;
#pragma unroll
        for (int q = 0; q < 4; q++) {
            const int ocol = cg * 64 + q * 16 + (l & 15);
#pragma unroll
            for (int r = 0; r < 4; r++)
                outp[(size_t)(orow + r) * DD + ocol] = acc[rb][q][r];
        }
    }
}

// -------- out = relu(p0+p1+p2+p3) --------
__global__ __launch_bounds__(256) void combine4(const float* __restrict__ p,
                                                float* __restrict__ out) {
    const size_t S = (size_t)NN * DD / 4;   // float4 stride between partials
    size_t idx = (size_t)blockIdx.x * 256 + threadIdx.x;
    float4 a = ((const float4*)p)[idx];
    float4 b = ((const float4*)p)[idx + S];
    float4 c = ((const float4*)p)[idx + 2 * S];
    float4 d = ((const float4*)p)[idx + 3 * S];
    float4 o;
    o.x = fmaxf(a.x + b.x + c.x + d.x, 0.f);
    o.y = fmaxf(a.y + b.y + c.y + d.y, 0.f);
    o.z = fmaxf(a.z + b.z + c.z + d.z, 0.f);
    o.w = fmaxf(a.w + b.w + c.w + d.w, 0.f);
    ((float4*)out)[idx] = o;
}

extern "C" void kernel_launch(void* const* d_in, const int* in_sizes, int n_in,
                              void* d_out, int out_size, void* d_ws, size_t ws_size,
                              hipStream_t stream) {
    const float* x   = (const float*)d_in[0];
    const int* adj   = (const int*)d_in[1];
    const float* W1  = (const float*)d_in[2];
    const float* a1s = (const float*)d_in[3];
    const float* a1d = (const float*)d_in[4];
    const float* W2  = (const float*)d_in[5];
    const float* a2s = (const float*)d_in[6];
    const float* a2d = (const float*)d_in[7];
    float* out = (float*)d_out;

    char* ws = (char*)d_ws;
    const size_t MB = 1024ull * 1024ull;
    float*          Wh    = (float*)(ws);                    // 8 MB
    uint64_t*       bits  = (uint64_t*)(ws + 8 * MB);        // 8 MB
    uint32_t*       bits32= (uint32_t*)bits;
    uint32_t*       bitsT = (uint32_t*)(ws + 16 * MB);       // 8 MB
    float*          sArr  = (float*)(ws + 24 * MB);
    float*          ddA   = sArr + NN;
    float*          EpA   = sArr + 2 * NN;
    float*          GpA   = sArr + 3 * NN;
    float*          FHA   = sArr + 4 * NN;                   // 2*NN floats
    unsigned short* Bpack = (unsigned short*)(ws + 25 * MB); // 4 MB
    float*          pout  = (float*)(ws + 32 * MB);          // 32 MB (4 partials)

    packbits<<<dim3(2048), dim3(256), 0, stream>>>(adj, bits);
    transp_bits<<<dim3(512), dim3(256), 0, stream>>>(bits32, bitsT);

    // ---------------- Layer 1 ----------------
    gemm_k256<<<dim3(1024), dim3(256), 0, stream>>>(x, W1, Wh, Bpack);
    rowdots<<<dim3(2048), dim3(256), 0, stream>>>(Wh, a1s, a1d, sArr, ddA, FHA);
    rowstats<<<dim3(2048), dim3(256), 0, stream>>>(bits32, sArr, ddA, FHA, EpA, GpA);
    pv_mfma<<<dim3(1024), dim3(256), 0, stream>>>(Bpack, bitsT, FHA, EpA, GpA, pout);
    combine4<<<dim3(2048), dim3(256), 0, stream>>>(pout, out);

    // ---------------- Layer 2 ----------------
    gemm_k256<<<dim3(1024), dim3(256), 0, stream>>>(out, W2, Wh, Bpack);
    rowdots<<<dim3(2048), dim3(256), 0, stream>>>(Wh, a2s, a2d, sArr, ddA, FHA);
    rowstats<<<dim3(2048), dim3(256), 0, stream>>>(bits32, sArr, ddA, FHA, EpA, GpA);
    pv_mfma<<<dim3(1024), dim3(256), 0, stream>>>(Bpack, bitsT, FHA, EpA, GpA, pout);
    combine4<<<dim3(2048), dim3(256), 0, stream>>>(pout, out);
}

// Round 12
// 666.287 us; speedup vs baseline: 3.0485x; 1.0057x over previous
//
#include <hip/hip_runtime.h>
#include <cstdint>
#include <cstddef>

// GAT 2-layer (N=8192, D=256), flash softmax with rank-1 scores, bf16 MFMA PV.
// Identities:
//   m_i = leaky(s_i + max_{adj} d_j)        (leaky monotone)
//   exp(leaky(x)) = max(e^x, e^{a x})
//   p_ij = adj ? max(Ep_i*F_j, Gp_i*H_j) : 0,  F=e^d, H=e^{a d} (FH interleaved),
//   Ep = rl*e^{s-m}, Gp = rl*e^{a s-m}.
// R12 pv v8: barrier-free, wave = 64 rows x 64 cols (4 A-frags x 4 B-frags =
// 16 MFMA/chunk -> 256 B-bytes per MFMA, half of v7). K-split x8, grid 1024 =
// 4 blocks/CU; __launch_bounds__(256,4) pins <=128 VGPR (16 waves/CU).
// No LDS, no __syncthreads in pv. combine8 reduces the 8 partials.
// ws: Wh @0 (8) | bits @8 (8) | bitsT @16 (8) | small @24 | Bpack @25 (4)
//     | pout @32 (8 x 8 MB k-split partials, ends @96 MB; ws is ~1 GB)

#define ALPHA 0.2f
#define NN 8192
#define DD 256

typedef __attribute__((ext_vector_type(8))) short short8;
typedef __attribute__((ext_vector_type(4))) float f32x4;

__device__ __forceinline__ unsigned bf16rne(float x) {
    union { float f; unsigned u; } c; c.f = x;
    return (c.u + 0x7fffu + ((c.u >> 16) & 1u)) >> 16;
}

#if __has_builtin(__builtin_amdgcn_cvt_pk_bf16_f32)
__device__ __forceinline__ unsigned pk_bf16(float a, float b) {
    return __builtin_bit_cast(unsigned, __builtin_amdgcn_cvt_pk_bf16_f32(a, b));
}
#else
__device__ __forceinline__ unsigned pk_bf16(float a, float b) {
    return bf16rne(a) | (bf16rne(b) << 16);
}
#endif

// ---------------- packbits: adj int32 [8192][8192] -> bits [8192][128] u64 ----------------
__global__ __launch_bounds__(256) void packbits(const int* __restrict__ adj,
                                                uint64_t* __restrict__ bits) {
    const int wid = blockIdx.x * 4 + (threadIdx.x >> 6);
    const int lane = threadIdx.x & 63;
    const int* rowp = adj + (size_t)wid * NN;
    uint64_t* dst = bits + (size_t)wid * 128;
    for (int it = 0; it < 32; it++) {
        const int* p = rowp + it * 256;
        int a0 = p[lane];
        int a1 = p[64 + lane];
        int a2 = p[128 + lane];
        int a3 = p[192 + lane];
        uint64_t m0 = __ballot(a0 != 0);
        uint64_t m1 = __ballot(a1 != 0);
        uint64_t m2 = __ballot(a2 != 0);
        uint64_t m3 = __ballot(a3 != 0);
        if (lane == 0) {
            dst[it * 4 + 0] = m0; dst[it * 4 + 1] = m1;
            dst[it * 4 + 2] = m2; dst[it * 4 + 3] = m3;
        }
    }
}

// ---------------- bits [i][w] -> bitsT [w][i] (64x64 dword tiles) ----------------
__global__ __launch_bounds__(256) void transp_bits(const uint32_t* __restrict__ bits32,
                                                   uint32_t* __restrict__ bitsT) {
    __shared__ uint32_t tile[64][65];
    const int t = threadIdx.x;
    const int i0 = (int)(blockIdx.x >> 2) * 64;
    const int w0 = (int)(blockIdx.x & 3) * 64;
#pragma unroll
    for (int p = 0; p < 4; p++) {
        int r = (t >> 4) + 16 * p;
        int c4 = (t & 15) * 4;
        uint4 v = *(const uint4*)(bits32 + (size_t)(i0 + r) * 256 + w0 + c4);
        tile[r][c4 + 0] = v.x; tile[r][c4 + 1] = v.y;
        tile[r][c4 + 2] = v.z; tile[r][c4 + 3] = v.w;
    }
    __syncthreads();
#pragma unroll
    for (int p = 0; p < 4; p++) {
        int wr = (t >> 4) + 16 * p;
        int i4 = (t & 15) * 4;
        uint4 o = {tile[i4][wr], tile[i4 + 1][wr], tile[i4 + 2][wr], tile[i4 + 3][wr]};
        *(uint4*)(bitsT + (size_t)(w0 + wr) * NN + i0 + i4) = o;
    }
}

// ---------------- GEMM: Wh[8192 x 256] = A @ B[256 x 256], fp32; packs Bpack ----------------
// 1024 blocks (4/CU): 256 row-tiles (32) x 4 col-quarters (64 cols).
__global__ __launch_bounds__(256) void gemm_k256(const float* __restrict__ A,
                                                 const float* __restrict__ B,
                                                 float* __restrict__ C,
                                                 unsigned short* __restrict__ Bpack) {
    __shared__ __align__(16) float At[32][36];
    __shared__ __align__(16) float2 Bs[32][32];
    const int t = threadIdx.x;
    const int m0 = (int)(blockIdx.x >> 2) * 32;
    const int cq = blockIdx.x & 3;
    const int r0 = (t >> 5) * 4;
    const int cl = t & 31;
    float acc[4][2];
#pragma unroll
    for (int i = 0; i < 4; i++) { acc[i][0] = 0.f; acc[i][1] = 0.f; }

    for (int k0 = 0; k0 < DD; k0 += 32) {
        {
            int row = t >> 3, kq = t & 7;
            float4 v = *(const float4*)(A + (size_t)(m0 + row) * DD + k0 + kq * 4);
            At[kq * 4 + 0][row] = v.x; At[kq * 4 + 1][row] = v.y;
            At[kq * 4 + 2][row] = v.z; At[kq * 4 + 3][row] = v.w;
        }
#pragma unroll
        for (int l2 = 0; l2 < 2; l2++) {
            int fi = l2 * 256 + t;
            int br = fi >> 4, bc4 = fi & 15;      // 32 k-rows x 16 float4 (64 cols)
            float4 v = *(const float4*)(B + (size_t)(k0 + br) * DD + cq * 64 + bc4 * 4);
            Bs[br][bc4 * 2] = {v.x, v.y};
            Bs[br][bc4 * 2 + 1] = {v.z, v.w};
        }
        __syncthreads();
#pragma unroll
        for (int k = 0; k < 32; k++) {
            float4 a0 = *(const float4*)&At[k][r0];
            float2 b = Bs[k][cl];
            float av[4] = {a0.x, a0.y, a0.z, a0.w};
#pragma unroll
            for (int i = 0; i < 4; i++) {
                acc[i][0] += av[i] * b.x;
                acc[i][1] += av[i] * b.y;
            }
        }
        __syncthreads();
    }
#pragma unroll
    for (int i = 0; i < 4; i++) {
        float2 v = {acc[i][0], acc[i][1]};
        *(float2*)(C + (size_t)(m0 + r0 + i) * DD + cq * 64 + cl * 2) = v;
    }
    const int jt = m0 >> 5;
    const int lq = ((r0 >> 3) & 3) * 16;
    const int i8 = r0 & 4;
#pragma unroll
    for (int cc = 0; cc < 2; cc++) {
        int c = cq * 64 + cl * 2 + cc;
        int ct = c >> 4;
        int lane = lq + (c & 15);
        uint2 pk;
        pk.x = pk_bf16(acc[0][cc], acc[1][cc]);
        pk.y = pk_bf16(acc[2][cc], acc[3][cc]);
        *(uint2*)(Bpack + ((size_t)(jt * 16 + ct) * 64 + lane) * 8 + i8) = pk;
    }
}

// ------- s,d row dots; FH[2i]=exp(d), FH[2i+1]=exp(a*d) (1 wave/row) -------
__global__ __launch_bounds__(256) void rowdots(const float* __restrict__ Wh,
                                               const float* __restrict__ a_src,
                                               const float* __restrict__ a_dst,
                                               float* __restrict__ s,
                                               float* __restrict__ dd,
                                               float* __restrict__ FH) {
    int wave = threadIdx.x >> 6;
    int lane = threadIdx.x & 63;
    int row = blockIdx.x * 4 + wave;
    float4 w = *(const float4*)(Wh + (size_t)row * DD + lane * 4);
    float4 as = *(const float4*)(a_src + lane * 4);
    float4 ad = *(const float4*)(a_dst + lane * 4);
    float ss = w.x * as.x + w.y * as.y + w.z * as.z + w.w * as.w;
    float sd = w.x * ad.x + w.y * ad.y + w.z * ad.z + w.w * ad.w;
#pragma unroll
    for (int off = 32; off; off >>= 1) {
        ss += __shfl_down(ss, off);
        sd += __shfl_down(sd, off);
    }
    if (lane == 0) {
        s[row] = ss; dd[row] = sd;
        FH[2 * row] = __expf(sd);
        FH[2 * row + 1] = __expf(ALPHA * sd);
    }
}

// ------ rowstats v4: 4 rows/block, 2048 blocks (8/CU, 32 waves/CU) ------
__global__ __launch_bounds__(256) void rowstats(const uint32_t* __restrict__ bits32,
                                                const float* __restrict__ s,
                                                const float* __restrict__ dd,
                                                const float* __restrict__ FH,
                                                float* __restrict__ Ep,
                                                float* __restrict__ Gp) {
    __shared__ uint32_t smk[1024];          // 4 rows x 256 words
    __shared__ float red[4][4];
    __shared__ float sEm[4], sEa[4];
    const int i0 = blockIdx.x * 4;
    const int t = threadIdx.x;
    const int wave = t >> 6, lane = t & 63;
    {
        const uint4* src = (const uint4*)(bits32 + (size_t)i0 * 256);
        ((uint4*)smk)[t] = src[t];
    }
    __syncthreads();

    float mx[4];
#pragma unroll
    for (int r = 0; r < 4; r++) mx[r] = -3.0e38f;
#pragma unroll
    for (int q = 0; q < 8; q++) {
        float4 v = *(const float4*)(dd + 4 * (t + 256 * q));
        const int wq = 32 * q + (t >> 3);
        const int sh = (t & 7) * 4;
#pragma unroll
        for (int r = 0; r < 4; r++) {
            uint32_t b = smk[r * 256 + wq] >> sh;
            mx[r] = fmaxf(mx[r], (b & 1u) ? v.x : -3.0e38f);
            mx[r] = fmaxf(mx[r], (b & 2u) ? v.y : -3.0e38f);
            mx[r] = fmaxf(mx[r], (b & 4u) ? v.z : -3.0e38f);
            mx[r] = fmaxf(mx[r], (b & 8u) ? v.w : -3.0e38f);
        }
    }
#pragma unroll
    for (int r = 0; r < 4; r++) {
#pragma unroll
        for (int off = 32; off; off >>= 1) mx[r] = fmaxf(mx[r], __shfl_down(mx[r], off));
    }
    if (lane == 0) {
#pragma unroll
        for (int r = 0; r < 4; r++) red[wave][r] = mx[r];
    }
    __syncthreads();
    if (t < 4) {
        float dmax = fmaxf(fmaxf(red[0][t], red[1][t]), fmaxf(red[2][t], red[3][t]));
        float si = s[i0 + t];
        float e = si + dmax;
        float m = e >= 0.f ? e : ALPHA * e;
        sEm[t] = __expf(si - m);
        sEa[t] = __expf(ALPHA * si - m);
    }
    __syncthreads();
    float em[4], ea[4], sm[4];
#pragma unroll
    for (int r = 0; r < 4; r++) { em[r] = sEm[r]; ea[r] = sEa[r]; sm[r] = 0.f; }

#pragma unroll
    for (int q = 0; q < 16; q++) {
        float4 v = *(const float4*)(FH + 4 * (t + 256 * q));
        const int wq = 16 * q + (t >> 4);
        const int sh = (t & 15) * 2;
#pragma unroll
        for (int r = 0; r < 4; r++) {
            uint32_t b = smk[r * 256 + wq] >> sh;
            float c0 = fmaxf(em[r] * v.x, ea[r] * v.y);
            float c1 = fmaxf(em[r] * v.z, ea[r] * v.w);
            sm[r] += (b & 1u) ? c0 : 0.f;
            sm[r] += (b & 2u) ? c1 : 0.f;
        }
    }
#pragma unroll
    for (int r = 0; r < 4; r++) {
#pragma unroll
        for (int off = 32; off; off >>= 1) sm[r] += __shfl_down(sm[r], off);
    }
    __syncthreads();
    if (lane == 0) {
#pragma unroll
        for (int r = 0; r < 4; r++) red[wave][r] = sm[r];
    }
    __syncthreads();
    if (t < 4) {
        float rl = 1.0f / (red[0][t] + red[1][t] + red[2][t] + red[3][t]);
        Ep[i0 + t] = rl * sEm[t];
        Gp[i0 + t] = rl * sEa[t];
    }
}

// ---------------- pv v8: barrier-free, wave = 64 rows x 64 cols, pout[ks] = P @ Wh ----------------
// 1024 blocks x 256 thr: bx -> ks = bx&7 (K-eighth, 32 chunks), cg = (bx>>3)&3,
// rowtile = bx>>5 (256 rows; wave w owns 64 rows at i0 = rowtile*256 + w*64).
// Per chunk: 4 B-frag loads + 4 bitsT dwords + 4 shared FH float4; 4 A-frags
// generated in registers; 16 MFMAs. NO LDS, NO barriers. <=128 VGPR (4 waves/EU).
__global__ __launch_bounds__(256, 4) void pv_mfma(const unsigned short* __restrict__ Bpack,
                                                  const uint32_t* __restrict__ bitsT,
                                                  const float* __restrict__ FH,
                                                  const float* __restrict__ Ep,
                                                  const float* __restrict__ Gp,
                                                  float* __restrict__ pout) {
    const int t = threadIdx.x;
    const int w = t >> 6, l = t & 63;
    const int bx = blockIdx.x;
    const int ks = bx & 7;
    const int cg = (bx >> 3) & 3;
    const int i0 = (bx >> 5) * 256 + w * 64;     // wave's 64-row base
    const int kbase = ks * 32;                   // 32 chunks per eighth

    const int rl16 = l & 15;
    const int ko = (l >> 4) * 8;                 // k-octet within 32-wide chunk
    const int r0 = i0 + rl16;
    float Epv[4], Gpv[4];
#pragma unroll
    for (int f = 0; f < 4; f++) {
        Epv[f] = Ep[r0 + 16 * f];
        Gpv[f] = Gp[r0 + 16 * f];
    }

    const unsigned short* bb = Bpack + ((size_t)(cg * 4) * 64 + l) * 8;
    const uint32_t* btb = bitsT + i0 + rl16;     // + cc*NN + 16*f

    f32x4 acc[4][4];
#pragma unroll
    for (int i = 0; i < 4; i++)
#pragma unroll
        for (int q = 0; q < 4; q++) acc[i][q] = (f32x4){0.f, 0.f, 0.f, 0.f};

    for (int jl = 0; jl < 32; jl++) {
        const int cc = kbase + jl;
        const unsigned short* bp = bb + (size_t)cc * 8192;
        short8 B0 = *(const short8*)(bp);
        short8 B1 = *(const short8*)(bp + 512);
        short8 B2 = *(const short8*)(bp + 1024);
        short8 B3 = *(const short8*)(bp + 1536);
        const uint32_t* btc = btb + (size_t)cc * NN;
        uint32_t bw0 = btc[0];
        uint32_t bw1 = btc[16];
        uint32_t bw2 = btc[32];
        uint32_t bw3 = btc[48];
        // shared FH for all 4 A-frags (same k-range)
        const float* fp = FH + 2 * (size_t)(cc * 32 + ko);
        float4 f0 = *(const float4*)(fp);
        float4 f1 = *(const float4*)(fp + 4);
        float4 f2 = *(const float4*)(fp + 8);
        float4 f3 = *(const float4*)(fp + 12);

        uint32_t bwa[4] = {bw0, bw1, bw2, bw3};
#pragma unroll
        for (int f = 0; f < 4; f++) {
            uint32_t wl = bwa[f] >> ko;
            float Epf = Epv[f], Gpf = Gpv[f];
            float p0 = (wl & 1u)   ? fmaxf(Epf * f0.x, Gpf * f0.y) : 0.f;
            float p1 = (wl & 2u)   ? fmaxf(Epf * f0.z, Gpf * f0.w) : 0.f;
            float p2 = (wl & 4u)   ? fmaxf(Epf * f1.x, Gpf * f1.y) : 0.f;
            float p3 = (wl & 8u)   ? fmaxf(Epf * f1.z, Gpf * f1.w) : 0.f;
            float p4 = (wl & 16u)  ? fmaxf(Epf * f2.x, Gpf * f2.y) : 0.f;
            float p5 = (wl & 32u)  ? fmaxf(Epf * f2.z, Gpf * f2.w) : 0.f;
            float p6 = (wl & 64u)  ? fmaxf(Epf * f3.x, Gpf * f3.y) : 0.f;
            float p7 = (wl & 128u) ? fmaxf(Epf * f3.z, Gpf * f3.w) : 0.f;
            uint4 au = {pk_bf16(p0, p1), pk_bf16(p2, p3), pk_bf16(p4, p5), pk_bf16(p6, p7)};
            short8 af = __builtin_bit_cast(short8, au);
            acc[f][0] = __builtin_amdgcn_mfma_f32_16x16x32_bf16(af, B0, acc[f][0], 0, 0, 0);
            acc[f][1] = __builtin_amdgcn_mfma_f32_16x16x32_bf16(af, B1, acc[f][1], 0, 0, 0);
            acc[f][2] = __builtin_amdgcn_mfma_f32_16x16x32_bf16(af, B2, acc[f][2], 0, 0, 0);
            acc[f][3] = __builtin_amdgcn_mfma_f32_16x16x32_bf16(af, B3, acc[f][3], 0, 0, 0);
        }
    }

    float* outp = pout + (size_t)ks * NN * DD;
    // C layout: col = l&15, row = (l>>4)*4 + r
#pragma unroll
    for (int f = 0; f < 4; f++) {
        const int orow = i0 + 16 * f + (l >> 4) * 4;
#pragma unroll
        for (int q = 0; q < 4; q++) {
            const int ocol = cg * 64 + q * 16 + rl16;
#pragma unroll
            for (int r = 0; r < 4; r++)
                outp[(size_t)(orow + r) * DD + ocol] = acc[f][q][r];
        }
    }
}

// -------- out = relu(sum of 8 partials) --------
__global__ __launch_bounds__(256) void combine8(const float* __restrict__ p,
                                                float* __restrict__ out) {
    const size_t S = (size_t)NN * DD / 4;   // float4 stride between partials
    size_t idx = (size_t)blockIdx.x * 256 + threadIdx.x;
    float4 a0 = ((const float4*)p)[idx];
    float4 a1 = ((const float4*)p)[idx + S];
    float4 a2 = ((const float4*)p)[idx + 2 * S];
    float4 a3 = ((const float4*)p)[idx + 3 * S];
    float4 a4 = ((const float4*)p)[idx + 4 * S];
    float4 a5 = ((const float4*)p)[idx + 5 * S];
    float4 a6 = ((const float4*)p)[idx + 6 * S];
    float4 a7 = ((const float4*)p)[idx + 7 * S];
    float4 o;
    o.x = fmaxf(((a0.x + a1.x) + (a2.x + a3.x)) + ((a4.x + a5.x) + (a6.x + a7.x)), 0.f);
    o.y = fmaxf(((a0.y + a1.y) + (a2.y + a3.y)) + ((a4.y + a5.y) + (a6.y + a7.y)), 0.f);
    o.z = fmaxf(((a0.z + a1.z) + (a2.z + a3.z)) + ((a4.z + a5.z) + (a6.z + a7.z)), 0.f);
    o.w = fmaxf(((a0.w + a1.w) + (a2.w + a3.w)) + ((a4.w + a5.w) + (a6.w + a7.w)), 0.f);
    ((float4*)out)[idx] = o;
}

extern "C" void kernel_launch(void* const* d_in, const int* in_sizes, int n_in,
                              void* d_out, int out_size, void* d_ws, size_t ws_size,
                              hipStream_t stream) {
    const float* x   = (const float*)d_in[0];
    const int* adj   = (const int*)d_in[1];
    const float* W1  = (const float*)d_in[2];
    const float* a1s = (const float*)d_in[3];
    const float* a1d = (const float*)d_in[4];
    const float* W2  = (const float*)d_in[5];
    const float* a2s = (const float*)d_in[6];
    const float* a2d = (const float*)d_in[7];
    float* out = (float*)d_out;

    char* ws = (char*)d_ws;
    const size_t MB = 1024ull * 1024ull;
    float*          Wh    = (float*)(ws);                    // 8 MB
    uint64_t*       bits  = (uint64_t*)(ws + 8 * MB);        // 8 MB
    uint32_t*       bits32= (uint32_t*)bits;
    uint32_t*       bitsT = (uint32_t*)(ws + 16 * MB);       // 8 MB
    float*          sArr  = (float*)(ws + 24 * MB);
    float*          ddA   = sArr + NN;
    float*          EpA   = sArr + 2 * NN;
    float*          GpA   = sArr + 3 * NN;
    float*          FHA   = sArr + 4 * NN;                   // 2*NN floats
    unsigned short* Bpack = (unsigned short*)(ws + 25 * MB); // 4 MB
    float*          pout  = (float*)(ws + 32 * MB);          // 64 MB (8 partials)

    packbits<<<dim3(2048), dim3(256), 0, stream>>>(adj, bits);
    transp_bits<<<dim3(512), dim3(256), 0, stream>>>(bits32, bitsT);

    // ---------------- Layer 1 ----------------
    gemm_k256<<<dim3(1024), dim3(256), 0, stream>>>(x, W1, Wh, Bpack);
    rowdots<<<dim3(2048), dim3(256), 0, stream>>>(Wh, a1s, a1d, sArr, ddA, FHA);
    rowstats<<<dim3(2048), dim3(256), 0, stream>>>(bits32, sArr, ddA, FHA, EpA, GpA);
    pv_mfma<<<dim3(1024), dim3(256), 0, stream>>>(Bpack, bitsT, FHA, EpA, GpA, pout);
    combine8<<<dim3(2048), dim3(256), 0, stream>>>(pout, out);

    // ---------------- Layer 2 ----------------
    gemm_k256<<<dim3(1024), dim3(256), 0, stream>>>(out, W2, Wh, Bpack);
    rowdots<<<dim3(2048), dim3(256), 0, stream>>>(Wh, a2s, a2d, sArr, ddA, FHA);
    rowstats<<<dim3(2048), dim3(256), 0, stream>>>(bits32, sArr, ddA, FHA, EpA, GpA);
    pv_mfma<<<dim3(1024), dim3(256), 0, stream>>>(Bpack, bitsT, FHA, EpA, GpA, pout);
    combine8<<<dim3(2048), dim3(256), 0, stream>>>(pout, out);
}